// Round 9
// baseline (211.757 us; speedup 1.0000x reference)
//
#include <hip/hip_runtime.h>

// ScaleDotProductAttention: B=2,H=16,S=2048,D=64 (fp32 in/out; bf16-adaptive).
// R16: dependency-chain cuts on R15. Evidence: VALU 35 + MFMA 31.5 = 66%
// issue-busy; the 34% residual stall resisted occupancy/pipe/issue diets ->
// intra-phase serial chain is the bottleneck. Changes:
//  (1) QK chain split 4->2 deep (sc0: dc{0,1}, sc1: dc{2,3}, 16 adds merge).
//  (2) V staged->direct per-wave register loads issued at phase start
//      (consumed after QK+exp; L2 latency hidden). K-only LDS staging ->
//      barrier payload halves, -4 ds_read/phase, LDS 24KB (16 stage + combine).

#define S_LEN 2048
#define D_DIM 64
#define WPR   32
#define NIT   32

typedef __attribute__((ext_vector_type(8)))  short bf16x8;
typedef __attribute__((ext_vector_type(4)))  float f32x4;
typedef __attribute__((ext_vector_type(16))) float f32x16;
typedef unsigned uint2v __attribute__((ext_vector_type(2)));
typedef unsigned long long ull;

__device__ __forceinline__ f32x16 mfma32(bf16x8 a, bf16x8 b, f32x16 c) {
  return __builtin_amdgcn_mfma_f32_32x32x16_bf16(a, b, c, 0, 0, 0);
}
__device__ __forceinline__ f32x4 mfma16(bf16x8 a, bf16x8 b, f32x4 c) {
  return __builtin_amdgcn_mfma_f32_16x16x32_bf16(a, b, c, 0, 0, 0);
}
__device__ __forceinline__ unsigned short f2bf(float f) {
  unsigned u = __builtin_bit_cast(unsigned, f);
  unsigned r = u + 0x7FFFu + ((u >> 16) & 1u);
  return (unsigned short)(r >> 16);
}
__device__ __forceinline__ float bf2f(unsigned short s) {
  unsigned u = ((unsigned)s) << 16;
  return __builtin_bit_cast(float, u);
}
__device__ __forceinline__ unsigned packbf(float a, float b) {
  // gfx950: v_cvt_pk_bf16_f32 (RNE), no clang builtin -> inline asm (T12).
  unsigned r;
  asm("v_cvt_pk_bf16_f32 %0, %1, %2" : "=v"(r) : "v"(a), "v"(b));
  return r;
}
__device__ __forceinline__ float fexp2(float x) {
#if __has_builtin(__builtin_amdgcn_exp2f)
  return __builtin_amdgcn_exp2f(x);
#else
  return exp2f(x);
#endif
}
__device__ __forceinline__ bool detect_bf16(const void* maskp) {
  const unsigned short* s = (const unsigned short*)maskp;
  unsigned short v = s[2 * (threadIdx.x & 63)];
  return __ballot(v == (unsigned short)0x3F80) != 0ull;
}
__device__ __forceinline__ int4 cvt_f8(const float* p) {
  float4 f0 = *(const float4*)p;
  float4 f1 = *(const float4*)(p + 4);
  int4 r;
  r.x = (int)packbf(f0.x, f0.y);
  r.y = (int)packbf(f0.z, f0.w);
  r.z = (int)packbf(f1.x, f1.y);
  r.w = (int)packbf(f1.z, f1.w);
  return r;
}
// Async 16B/lane global->LDS. g is PER-LANE src; dest = l + lane*16B (HW).
__device__ __forceinline__ void gl_lds16(const unsigned short* g, unsigned short* l) {
#if __has_builtin(__builtin_amdgcn_global_load_lds)
  __builtin_amdgcn_global_load_lds(
      (const __attribute__((address_space(1))) unsigned int*)g,
      (__attribute__((address_space(3))) unsigned int*)l, 16, 0, 0);
#else
  *(int4*)((char*)l + (threadIdx.x & 63) * 16) = *(const int4*)g;
#endif
}

#define C1 0.18033688011112042f     /* (1/sqrt(64))*log2(e) */
#define C2 1.4426950408889634e9f

#define SEG0 4096u
#define SEG1 2048u
#define SEG2 1024u
#define SEG3 2048u

// ---------------- unified prepass ----------------
// seg0 (4096):  mask -> bits (8 elems/thread), transposed: bits[((b*32+word)<<11)+row]
// seg1 (2048):  K -> Kf 32x32 A-frags           [skipped when bf16 inputs]
// seg2 (1024):  V -> Vf 32x32 B-frags
// seg3 (2048):  Q -> Qc bf16 row-major, *C1     [skipped when bf16 inputs]
__global__ __launch_bounds__(256) void prep_all(
    const void* __restrict__ M, const void* __restrict__ Kin,
    const void* __restrict__ Vin, const void* __restrict__ Qin,
    ull* __restrict__ bits, unsigned short* __restrict__ Kf,
    unsigned short* __restrict__ Vf, unsigned short* __restrict__ Qc) {
  __shared__ __align__(16) unsigned short T[64 * 72];
  const bool isb = detect_bf16(M);
  const unsigned bx = blockIdx.x;
  const int tid = threadIdx.x;

  if (bx < SEG0) {            // ---- mask bits, 8 elements per thread
    unsigned e0 = bx * 2048u + tid;
    #pragma unroll
    for (int j = 0; j < 8; ++j) {
      unsigned idx = e0 + (unsigned)j * 256u;
      bool on = isb ? (bf2f(((const unsigned short*)M)[idx]) > 0.5f)
                    : (((const float*)M)[idx] > 0.5f);
      ull bm = __ballot(on);
      if ((tid & 63) == 0) {
        unsigned c = idx & 2047u, r = (idx >> 11) & 2047u, bb = idx >> 22;
        bits[(((size_t)(bb * WPR + (c >> 6))) << 11) + r] = bm;
      }
    }
  } else if (bx < SEG0 + SEG1) {   // ---- Kf gather (fp32 inputs only)
    if (isb) return;
    unsigned g = (bx - SEG0) * 256u + tid;
    unsigned lane = g & 63u, f = (g >> 6) & 7u, it = (g >> 9) & 31u, bh = g >> 14;
    unsigned t = f >> 2, dc = f & 3, hi = lane >> 5, l31 = lane & 31;
    size_t src = (size_t)bh * (S_LEN * D_DIM) +
                 (size_t)(it * 64 + t * 32 + l31) * D_DIM + dc * 16 + hi * 8;
    *(int4*)&Kf[(size_t)g * 8] = cvt_f8((const float*)Kin + src);
  } else if (bx < SEG0 + SEG1 + SEG2) {  // ---- Vf transpose via LDS
    unsigned idx = bx - (SEG0 + SEG1);
    unsigned bh = idx >> 5, it = idx & 31u;
    {
      int k = tid >> 2, d0 = (tid & 3) * 16;
      size_t src = (size_t)bh * (S_LEN * D_DIM) + (size_t)(it * 64 + k) * D_DIM + d0;
      int4 a, c;
      if (isb) {
        const unsigned short* s = (const unsigned short*)Vin + src;
        a = *(const int4*)s; c = *(const int4*)(s + 8);
      } else {
        const float* s = (const float*)Vin + src;
        a = cvt_f8(s); c = cvt_f8(s + 8);
      }
      *(int4*)&T[k * 72 + d0] = a;
      *(int4*)&T[k * 72 + d0 + 8] = c;
    }
    __syncthreads();
    #pragma unroll
    for (int h = 0; h < 2; ++h) {
      int c = tid + h * 256;
      int lane = c & 63, f = c >> 6;
      int t = f >> 2, kc = (f >> 1) & 1, dt = f & 1;
      int hi = lane >> 5, l31 = lane & 31;
      unsigned short v[8];
      #pragma unroll
      for (int j = 0; j < 8; ++j)
        v[j] = T[(t * 32 + kc * 16 + hi * 8 + j) * 72 + dt * 32 + l31];
      *(int4*)&Vf[(((size_t)(bh * 32 + it)) * 8 + f) * 512 + lane * 8] = *(int4*)v;
    }
  } else {                       // ---- Qc (fp32 inputs only)
    if (isb) return;
    size_t i0 = ((size_t)(bx - (SEG0 + SEG1 + SEG2)) * 256 + tid) * 8;
    unsigned short v[8];
    const float* f = (const float*)Qin + i0;
    #pragma unroll
    for (int j = 0; j < 4; ++j)
      *((unsigned*)v + j) = packbf(f[2 * j] * C1, f[2 * j + 1] * C1);
    *(int4*)&Qc[i0] = *(int4*)v;
  }
}

// ---------------- prep_w: in-place ballot-transpose bits -> lane-masks -------
// Unit (1 wave): (b, w, q32). Reads 32 ulls bits[((b*32+w)<<11) + q32*32 + j],
// emits 32 ulls W[sub*16+r] at the SAME 32-ull window:
//   bit l of W = bit (sub*32 + (r&3)+8*(r>>2)+4*(l>>5)) of row (q32*32+(l&31)).
// Disjoint windows across units -> in-place safe.
__global__ __launch_bounds__(256) void prep_w(ull* __restrict__ bits) {
  const int tid = threadIdx.x;
  const int wave = tid >> 6;
  const int lane = tid & 63;
  const int hi = lane >> 5;
  const unsigned uid = blockIdx.x * 4 + wave;    // 0..4095
  const unsigned b = uid >> 11, w = (uid >> 6) & 31u, q32 = uid & 63u;
  ull* base = bits + (((size_t)(b * 32 + w)) << 11) + (size_t)q32 * 32;
  const ull wc = base[lane & 31];
  #pragma unroll
  for (int sub = 0; sub < 2; ++sub) {
    #pragma unroll
    for (int r = 0; r < 16; ++r) {
      int pos = sub * 32 + (r & 3) + 8 * (r >> 2) + 4 * hi;
      ull W = __ballot(((wc >> pos) & 1ull) != 0ull);
      if (lane == 0) base[sub * 16 + r] = W;
    }
  }
}

// ---------------- split-K attention: K-staged, V-in-reg, split QK chain ------
// grid 1024: id -> xcd=id&7, slot=id>>3; bh=(id&7)*4+(slot&3); qb=slot>>2.
// Block = 64 q-rows. Wave w: g=w>>1 sweeps subtiles [g*32,+32), rw=w&1 rows.
// Mask: per-phase 16 wave-uniform lane-mask ulls (s_load) + v_cndmask.
__global__ __launch_bounds__(256, 4) void attn_fast(
    const unsigned short* __restrict__ Qc, const void* __restrict__ Qraw,
    const unsigned short* __restrict__ Kf, const void* __restrict__ Kraw,
    const unsigned short* __restrict__ Vf, const ull* __restrict__ Wm,
    const void* __restrict__ maskp, void* __restrict__ Op) {
  // 24KB: K staging [2 grp][2 buf][4 frag][1KB] = 16KB, combine overlay 24KB.
  __shared__ __align__(16) char ShMem[24576];
  typedef unsigned short StgT[2][4][512];
  StgT* Stg = (StgT*)ShMem;                       // Stg[g][buf][frag][idx]

  const bool isb = detect_bf16(maskp);
  const int tid  = threadIdx.x;
  const int wave = tid >> 6;
  const int lane = tid & 63;
  const int hi   = lane >> 5;
  const int l31  = lane & 31;
  const int wvu  = __builtin_amdgcn_readfirstlane(wave);
  const int g    = wvu >> 1;        // k-half (uniform)
  const int rw   = wvu & 1;         // row-half (uniform)
  const int id   = blockIdx.x;
  const int slot = id >> 3;
  const int bh   = (id & 7) * 4 + (slot & 3);   // XCD-affine: 4 bh per XCD
  const int qb   = slot >> 2;                   // 0..31
  const int qbase = qb * 64 + rw * 32;          // this wave's 32 q-rows
  const int b    = bh >> 4;
  const size_t base = (size_t)bh * S_LEN * D_DIM;
  const int xidx = ((lane ^ 32) & 63) * 4;      // ds_bpermute byte index

  // Q B-fragments: bf16, scaled by C1 (direct-read when bf16 inputs)
  bf16x8 qf[4];
  if (isb) {
    #pragma unroll
    for (int dc = 0; dc < 4; ++dc) {
      bf16x8 q = *(const bf16x8*)((const unsigned short*)Qraw + base +
                    (size_t)(qbase + l31) * D_DIM + dc * 16 + hi * 8);
      #pragma unroll
      for (int j = 0; j < 8; ++j)
        q[j] = (short)f2bf(bf2f((unsigned short)q[j]) * C1);
      qf[dc] = q;
    }
  } else {
    #pragma unroll
    for (int dc = 0; dc < 4; ++dc)
      qf[dc] = *(const bf16x8*)&Qc[base + (size_t)(qbase + l31) * D_DIM + dc * 16 + hi * 8];
  }

  // ones B-fragment (all bf16 1.0) for row-sum MFMA
  bf16x8 onesb;
  #pragma unroll
  for (int i = 0; i < 8; ++i) onesb[i] = (short)0x3F80;

  // K staging source: per-lane gather (bf16 direct) or Kf linear (fp32 path).
  const unsigned short* Kw0;
  size_t kd;
  if (isb) {
    Kw0 = (const unsigned short*)Kraw + base + (size_t)l31 * D_DIM + (2 * rw) * 16 + hi * 8;
    kd = 16;
  } else {
    Kw0 = Kf + (size_t)bh * 131072 + (size_t)(2 * rw) * 512 + lane * 8;
    kd = 512;
  }
  // V read base (per-lane, register loads)
  const unsigned short* Vb = Vf + (size_t)bh * 131072 + lane * 8;
  const int ks0 = g * 32;

  // wave-uniform lane-mask table base (ull units)
  const ull* WmU = Wm + (((size_t)(b * 32)) << 11) + (size_t)(qb * 2 + rw) * 32;

  f32x16 acc_o[2];   // [dt]: O[m=(reg&3)+8(reg>>2)+4hi][d=dt*32+l31] (unnormalized)
  f32x16 acc_l;      // row-sums, same row mapping
  f32x16 zv;         // persistent zero C-operand
  #pragma unroll
  for (int r = 0; r < 16; ++r) {
    acc_o[0][r] = 0.f; acc_o[1][r] = 0.f; acc_l[r] = 0.f; zv[r] = 0.f;
  }

  // prologue: stage K of subtile ks0 into buf 0
  {
    const size_t so = (size_t)ks0 * 2048;
    gl_lds16(Kw0 + so,      &Stg[g][0][2 * rw][0]);
    gl_lds16(Kw0 + so + kd, &Stg[g][0][2 * rw + 1][0]);
  }
  __syncthreads();

  #pragma unroll 2
  for (int f = 0; f < 32; ++f) {
    const int cur = f & 1;
    const int ks = ks0 + f;
    // V frags for THIS subtile: private register loads, issued first
    // (consumed after QK+exp -> L2 latency hidden under compute)
    bf16x8 vv[4];
    {
      const unsigned short* Vp_ = Vb + (size_t)ks * 2048;
      #pragma unroll
      for (int fi = 0; fi < 4; ++fi)
        vv[fi] = *(const bf16x8*)(Vp_ + (size_t)fi * 512);
    }
    // stage next subtile's K into the other buffer (flies under compute)
    if (f < 31) {
      const size_t so = (size_t)(ks + 1) * 2048;
      gl_lds16(Kw0 + so,      &Stg[g][cur ^ 1][2 * rw][0]);
      gl_lds16(Kw0 + so + kd, &Stg[g][cur ^ 1][2 * rw + 1][0]);
    }
    // per-phase lane-mask words (wave-uniform -> s_load)
    const ull* Wp = WmU + (((size_t)(ks >> 1)) << 11) + (size_t)(ks & 1) * 16;

    // QK^T: two independent 2-deep chains (was one 4-deep chain)
    bf16x8 ka[4];
    #pragma unroll
    for (int dc = 0; dc < 4; ++dc)
      ka[dc] = *(const bf16x8*)&Stg[g][cur][dc][lane * 8];
    __builtin_amdgcn_s_setprio(1);
    f32x16 sc0 = mfma32(ka[0], qf[0], zv);
    f32x16 sc1 = mfma32(ka[2], qf[2], zv);
    sc0 = mfma32(ka[1], qf[1], sc0);
    sc1 = mfma32(ka[3], qf[3], sc1);
    __builtin_amdgcn_s_setprio(0);

    // merge halves + exp2 + mask (one cndmask per slot, SGPR-pair mask)
    float p[16];
    #pragma unroll
    for (int r = 0; r < 16; ++r) {
      float e = fexp2(sc0[r] + sc1[r]);
      ull mr = Wp[r];
      asm("v_cndmask_b32 %0, %1, 0, %2" : "=v"(p[r]) : "v"(e), "s"(mr));
    }

    #pragma unroll
    for (int kc = 0; kc < 2; ++kc) {
      unsigned pk0 = packbf(p[8 * kc + 0], p[8 * kc + 1]);
      unsigned pk1 = packbf(p[8 * kc + 2], p[8 * kc + 3]);
      unsigned pk2 = packbf(p[8 * kc + 4], p[8 * kc + 5]);
      unsigned pk3 = packbf(p[8 * kc + 6], p[8 * kc + 7]);
      uint4 d;
#if __has_builtin(__builtin_amdgcn_permlane32_swap)
      uint2v s02 = __builtin_amdgcn_permlane32_swap(pk0, pk2, false, false);
      uint2v s13 = __builtin_amdgcn_permlane32_swap(pk1, pk3, false, false);
      d.x = s02[0]; d.z = s02[1];
      d.y = s13[0]; d.w = s13[1];
#else
      unsigned x0 = (unsigned)__builtin_amdgcn_ds_bpermute(xidx, (int)pk0);
      unsigned x1 = (unsigned)__builtin_amdgcn_ds_bpermute(xidx, (int)pk1);
      unsigned x2 = (unsigned)__builtin_amdgcn_ds_bpermute(xidx, (int)pk2);
      unsigned x3 = (unsigned)__builtin_amdgcn_ds_bpermute(xidx, (int)pk3);
      d.x = hi ? x2 : pk0;
      d.y = hi ? x3 : pk1;
      d.z = hi ? pk2 : x0;
      d.w = hi ? pk3 : x1;
#endif
      bf16x8 pf = __builtin_bit_cast(bf16x8, d);
      __builtin_amdgcn_s_setprio(1);
      #pragma unroll
      for (int dt = 0; dt < 2; ++dt)
        acc_o[dt] = mfma32(pf, vv[kc * 2 + dt], acc_o[dt]);
      acc_l = mfma32(pf, onesb, acc_l);   // row-sum on the MFMA pipe
      __builtin_amdgcn_s_setprio(0);
    }

    // one barrier per phase: next K stage landed + buf[cur] safe to restage
    __syncthreads();
  }

  // ---- cross-group combine via retired ShMem (fixed-max -> pure sums)
  float* Cb = (float*)ShMem;
  if (g == 1) {
    #pragma unroll
    for (int r = 0; r < 16; ++r) {
      Cb[(rw * 48 + r) * 64 + lane]      = acc_o[0][r];
      Cb[(rw * 48 + 16 + r) * 64 + lane] = acc_o[1][r];
      Cb[(rw * 48 + 32 + r) * 64 + lane] = acc_l[r];
    }
  }
  __syncthreads();
  if (g == 0) {
    #pragma unroll
    for (int r = 0; r < 16; ++r) {
      float o0 = acc_o[0][r] + Cb[(rw * 48 + r) * 64 + lane];
      float o1 = acc_o[1][r] + Cb[(rw * 48 + 16 + r) * 64 + lane];
      float lv = acc_l[r]    + Cb[(rw * 48 + 32 + r) * 64 + lane];
      int m = (r & 3) + 8 * (r >> 2) + 4 * hi;
      float inv = 1.0f / lv;
      size_t idx = base + (size_t)(qbase + m) * D_DIM + l31;
      if (isb) {
        ((unsigned short*)Op)[idx]      = f2bf(o0 * inv);
        ((unsigned short*)Op)[idx + 32] = f2bf(o1 * inv);
      } else {
        ((float*)Op)[idx]      = o0 * inv;
        ((float*)Op)[idx + 32] = o1 * inv;
      }
    }
  }
}

// ---------------- no-workspace fallback (R2-proven structure) ----------------
__global__ __launch_bounds__(256, 2) void attn_fallback(
    const void* __restrict__ Qp, const void* __restrict__ Kp,
    const void* __restrict__ Vp, const void* __restrict__ maskp,
    void* __restrict__ Op) {
  __shared__ __align__(16) short QKlds[128 * 72];
  __shared__ __align__(16) short Vtlds[64 * 72];
  __shared__ __align__(16) short Plds2[128 * 72];

  const bool isb = detect_bf16(maskp);
  const int tid  = threadIdx.x;
  const int wave = tid >> 6;
  const int lane = tid & 63;
  const int l15  = lane & 15;
  const int quad = lane >> 4;
  const int q0   = blockIdx.x * 128;
  const int bh   = blockIdx.y;
  const int b    = bh >> 4;
  const size_t base = (size_t)bh * S_LEN * D_DIM;

  const short* Qs = (const short*)Qp; const float* Qf = (const float*)Qp;
  const short* Ks = (const short*)Kp; const float* Kf2 = (const float*)Kp;
  const short* Vs = (const short*)Vp; const float* Vf2 = (const float*)Vp;

  if (isb) {
    const short* Qg = Qs + base + (size_t)q0 * D_DIM;
    #pragma unroll
    for (int p = 0; p < 4; ++p) {
      int e = p * 2048 + tid * 8;
      *(int4*)&QKlds[(e >> 6) * 72 + (e & 63)] = *(const int4*)(Qg + e);
    }
  } else {
    const float* Qg = Qf + base + (size_t)q0 * D_DIM;
    #pragma unroll
    for (int p = 0; p < 4; ++p) {
      int e = p * 2048 + tid * 8;
      *(int4*)&QKlds[(e >> 6) * 72 + (e & 63)] = cvt_f8(Qg + e);
    }
  }
  __syncthreads();
  bf16x8 qf[2][2];
  #pragma unroll
  for (int mi = 0; mi < 2; ++mi)
    #pragma unroll
    for (int kt = 0; kt < 2; ++kt)
      qf[mi][kt] = *(const bf16x8*)&QKlds[(wave * 32 + mi * 16 + l15) * 72 + kt * 32 + quad * 8];
  __syncthreads();

  f32x4 acc_o[2][4];
  f32x4 acc_l[2];
  const f32x4 zero4 = {0.f, 0.f, 0.f, 0.f};
  #pragma unroll
  for (int mi = 0; mi < 2; ++mi) {
    acc_l[mi] = zero4;
    #pragma unroll
    for (int nt = 0; nt < 4; ++nt) acc_o[mi][nt] = zero4;
  }
  bf16x8 onesB;
  {
    short ov = (l15 == 0) ? (short)0x3F80 : (short)0;
    #pragma unroll
    for (int i = 0; i < 8; ++i) onesB[i] = ov;
  }

  for (int it = 0; it < NIT; ++it) {
    const int k0 = it * 64;
    if (isb) {
      const short* Kg = Ks + base + (size_t)k0 * D_DIM;
      #pragma unroll
      for (int p = 0; p < 2; ++p) {
        int e = p * 2048 + tid * 8;
        *(int4*)&QKlds[(e >> 6) * 72 + (e & 63)] = *(const int4*)(Kg + e);
      }
    } else {
      const float* Kg = Kf2 + base + (size_t)k0 * D_DIM;
      #pragma unroll
      for (int p = 0; p < 2; ++p) {
        int e = p * 2048 + tid * 8;
        *(int4*)&QKlds[(e >> 6) * 72 + (e & 63)] = cvt_f8(Kg + e);
      }
    }
    {
      const int r0 = (tid >> 3) * 2;
      const int d0 = (tid & 7) * 8;
      unsigned short as_[8], bs_[8];
      if (isb) {
        const short* Vg = Vs + base + (size_t)k0 * D_DIM;
        *(int4*)as_ = *(const int4*)(Vg + r0 * D_DIM + d0);
        *(int4*)bs_ = *(const int4*)(Vg + (r0 + 1) * D_DIM + d0);
      } else {
        const float* Vg = Vf2 + base + (size_t)k0 * D_DIM;
        *(int4*)as_ = cvt_f8(Vg + r0 * D_DIM + d0);
        *(int4*)bs_ = cvt_f8(Vg + (r0 + 1) * D_DIM + d0);
      }
      #pragma unroll
      for (int j = 0; j < 8; ++j) {
        int d = d0 + j;
        int blk = (r0 >> 3) ^ (d >> 3);
        unsigned pk = (unsigned)as_[j] | ((unsigned)bs_[j] << 16);
        *(unsigned*)&Vtlds[d * 72 + blk * 8 + (r0 & 7)] = pk;
      }
    }
    __syncthreads();

    f32x4 sc[2][4];
    #pragma unroll
    for (int mi = 0; mi < 2; ++mi)
      #pragma unroll
      for (int nt = 0; nt < 4; ++nt) sc[mi][nt] = zero4;
    #pragma unroll
    for (int nt = 0; nt < 4; ++nt) {
      bf16x8 kf0 = *(const bf16x8*)&QKlds[(nt * 16 + l15) * 72 + quad * 8];
      bf16x8 kf1 = *(const bf16x8*)&QKlds[(nt * 16 + l15) * 72 + 32 + quad * 8];
      #pragma unroll
      for (int mi = 0; mi < 2; ++mi) {
        sc[mi][nt] = mfma16(qf[mi][0], kf0, sc[mi][nt]);
        sc[mi][nt] = mfma16(qf[mi][1], kf1, sc[mi][nt]);
      }
    }

    #pragma unroll
    for (int mi = 0; mi < 2; ++mi) {
      #pragma unroll
      for (int nt = 0; nt < 4; ++nt) {
        #pragma unroll
        for (int reg = 0; reg < 4; ++reg) {
          int rg = q0 + wave * 32 + mi * 16 + quad * 4 + reg;
          size_t mix = (size_t)b * S_LEN * S_LEN + (size_t)rg * S_LEN + k0 + nt * 16 + l15;
          float mv = isb ? bf2f(((const unsigned short*)maskp)[mix])
                         : ((const float*)maskp)[mix];
          float y = sc[mi][nt][reg] * C1 - mv * C2;
          Plds2[(wave * 32 + mi * 16 + quad * 4 + reg) * 72 + nt * 16 + l15] =
              (short)f2bf(fexp2(y));
        }
      }
    }
    __syncthreads();

    #pragma unroll
    for (int kt = 0; kt < 2; ++kt) {
      bf16x8 pf[2];
      #pragma unroll
      for (int mi = 0; mi < 2; ++mi)
        pf[mi] = *(const bf16x8*)&Plds2[(wave * 32 + mi * 16 + l15) * 72 + kt * 32 + quad * 8];
      #pragma unroll
      for (int nt = 0; nt < 4; ++nt) {
        int d = nt * 16 + l15;
        int kb = (kt * 4 + quad) ^ (d >> 3);
        bf16x8 vf = *(const bf16x8*)&Vtlds[d * 72 + kb * 8];
        #pragma unroll
        for (int mi = 0; mi < 2; ++mi)
          acc_o[mi][nt] = mfma16(pf[mi], vf, acc_o[mi][nt]);
      }
      #pragma unroll
      for (int mi = 0; mi < 2; ++mi)
        acc_l[mi] = mfma16(pf[mi], onesB, acc_l[mi]);
    }
    __syncthreads();
  }

  #pragma unroll
  for (int mi = 0; mi < 2; ++mi) {
    #pragma unroll
    for (int reg = 0; reg < 4; ++reg) {
      float lv = __shfl(acc_l[mi][reg], lane & 48, 64);
      float inv = 1.0f / lv;
      #pragma unroll
      for (int nt = 0; nt < 4; ++nt) {
        float o = acc_o[mi][nt][reg] * inv;
        size_t idx = base + (size_t)(q0 + wave * 32 + mi * 16 + quad * 4 + reg) * D_DIM + nt * 16 + l15;
        if (isb) ((unsigned short*)Op)[idx] = f2bf(o);
        else     ((float*)Op)[idx] = o;
      }
    }
  }
}

extern "C" void kernel_launch(void* const* d_in, const int* in_sizes, int n_in,
                              void* d_out, int out_size, void* d_ws, size_t ws_size,
                              hipStream_t stream) {
  const void* Q = d_in[0];
  const void* K = d_in[1];
  const void* V = d_in[2];
  const void* M = d_in[3];

  dim3 block(256);
  const size_t bits_bytes = (size_t)2 * S_LEN * S_LEN / 8;          // 1 MB
  const size_t tens_bytes = (size_t)2 * 16 * S_LEN * D_DIM * 2;     // 8.4 MB bf16

  if (ws_size >= bits_bytes + 3 * tens_bytes) {
    char* ws = (char*)d_ws;
    ull* bits = (ull*)ws;
    unsigned short* Kf = (unsigned short*)(ws + bits_bytes);
    unsigned short* Vf = (unsigned short*)(ws + bits_bytes + tens_bytes);
    unsigned short* Qc = (unsigned short*)(ws + bits_bytes + 2 * tens_bytes);
    prep_all<<<dim3(SEG0 + SEG1 + SEG2 + SEG3), block, 0, stream>>>(
        M, K, V, Q, bits, Kf, Vf, Qc);
    prep_w<<<dim3(1024), block, 0, stream>>>(bits);
    attn_fast<<<dim3(1024), block, 0, stream>>>(Qc, Q, Kf, K, Vf, bits, M, d_out);
  } else {
    attn_fallback<<<dim3(S_LEN / 128, 32), block, 0, stream>>>(Q, K, V, M, d_out);
  }
}

// Round 10
// 168.413 us; speedup vs baseline: 1.2574x; 1.2574x over previous
//
#include <hip/hip_runtime.h>

// ScaleDotProductAttention: B=2,H=16,S=2048,D=64 (fp32 in/out; bf16-adaptive).
// R17: revert to R15 (best: 57.0us attn) after R16's spill regression
// (WRITE_SIZE 16->37MB = scratch). Two additive, budget-safe changes:
//  (1) QK chain split 4->2 deep (sc0/sc1 + 16-add merge); V stays LDS-staged
//      so peak regs ~72-88 < 128 (R16 spilled because V-in-reg stacked on top).
//  (2) prep_w fused into prep_all seg0: block = 32-row x 64-col mask tile,
//      per-row ballots -> LDS -> in-block ballot-transpose -> final lane-masks.
//      Kills the prep_w launch + 2MB bits round-trip.

#define S_LEN 2048
#define D_DIM 64
#define WPR   32
#define NIT   32

typedef __attribute__((ext_vector_type(8)))  short bf16x8;
typedef __attribute__((ext_vector_type(4)))  float f32x4;
typedef __attribute__((ext_vector_type(16))) float f32x16;
typedef unsigned uint2v __attribute__((ext_vector_type(2)));
typedef unsigned long long ull;

__device__ __forceinline__ f32x16 mfma32(bf16x8 a, bf16x8 b, f32x16 c) {
  return __builtin_amdgcn_mfma_f32_32x32x16_bf16(a, b, c, 0, 0, 0);
}
__device__ __forceinline__ f32x4 mfma16(bf16x8 a, bf16x8 b, f32x4 c) {
  return __builtin_amdgcn_mfma_f32_16x16x32_bf16(a, b, c, 0, 0, 0);
}
__device__ __forceinline__ unsigned short f2bf(float f) {
  unsigned u = __builtin_bit_cast(unsigned, f);
  unsigned r = u + 0x7FFFu + ((u >> 16) & 1u);
  return (unsigned short)(r >> 16);
}
__device__ __forceinline__ float bf2f(unsigned short s) {
  unsigned u = ((unsigned)s) << 16;
  return __builtin_bit_cast(float, u);
}
__device__ __forceinline__ unsigned packbf(float a, float b) {
  // gfx950: v_cvt_pk_bf16_f32 (RNE), no clang builtin -> inline asm (T12).
  unsigned r;
  asm("v_cvt_pk_bf16_f32 %0, %1, %2" : "=v"(r) : "v"(a), "v"(b));
  return r;
}
__device__ __forceinline__ float fexp2(float x) {
#if __has_builtin(__builtin_amdgcn_exp2f)
  return __builtin_amdgcn_exp2f(x);
#else
  return exp2f(x);
#endif
}
__device__ __forceinline__ bool detect_bf16(const void* maskp) {
  const unsigned short* s = (const unsigned short*)maskp;
  unsigned short v = s[2 * (threadIdx.x & 63)];
  return __ballot(v == (unsigned short)0x3F80) != 0ull;
}
__device__ __forceinline__ int4 cvt_f8(const float* p) {
  float4 f0 = *(const float4*)p;
  float4 f1 = *(const float4*)(p + 4);
  int4 r;
  r.x = (int)packbf(f0.x, f0.y);
  r.y = (int)packbf(f0.z, f0.w);
  r.z = (int)packbf(f1.x, f1.y);
  r.w = (int)packbf(f1.z, f1.w);
  return r;
}
// Async 16B/lane global->LDS. g is PER-LANE src; dest = l + lane*16B (HW).
__device__ __forceinline__ void gl_lds16(const unsigned short* g, unsigned short* l) {
#if __has_builtin(__builtin_amdgcn_global_load_lds)
  __builtin_amdgcn_global_load_lds(
      (const __attribute__((address_space(1))) unsigned int*)g,
      (__attribute__((address_space(3))) unsigned int*)l, 16, 0, 0);
#else
  *(int4*)((char*)l + (threadIdx.x & 63) * 16) = *(const int4*)g;
#endif
}

#define C1 0.18033688011112042f     /* (1/sqrt(64))*log2(e) */
#define C2 1.4426950408889634e9f

#define SEG0 4096u
#define SEG1 2048u
#define SEG2 1024u
#define SEG3 2048u

// ---------------- unified prepass ----------------
// seg0 (4096):  mask tile (32 rows x 64 cols) -> FINAL lane-masks (fused prep_w)
// seg1 (2048):  K -> Kf 32x32 A-frags           [skipped when bf16 inputs]
// seg2 (1024):  V -> Vf 32x32 B-frags
// seg3 (2048):  Q -> Qc bf16 row-major, *C1     [skipped when bf16 inputs]
__global__ __launch_bounds__(256) void prep_all(
    const void* __restrict__ M, const void* __restrict__ Kin,
    const void* __restrict__ Vin, const void* __restrict__ Qin,
    ull* __restrict__ bits, unsigned short* __restrict__ Kf,
    unsigned short* __restrict__ Vf, unsigned short* __restrict__ Qc) {
  __shared__ __align__(16) unsigned short T[64 * 72];
  __shared__ ull rowb[32];
  const bool isb = detect_bf16(M);
  const unsigned bx = blockIdx.x;
  const int tid = threadIdx.x;

  if (bx < SEG0) {   // ---- mask -> lane-masks, one (bb, q32, w) tile per block
    const unsigned bb = bx >> 11, q32 = (bx >> 5) & 63u, w = bx & 31u;
    const int wv = tid >> 6, l = tid & 63;
    #pragma unroll
    for (int j = 0; j < 8; ++j) {
      int rl = j * 4 + wv;                       // row_local 0..31
      size_t midx = ((size_t)(bb * 2048u + q32 * 32u + rl)) * 2048u + w * 64u + l;
      bool on = isb ? (bf2f(((const unsigned short*)M)[midx]) > 0.5f)
                    : (((const float*)M)[midx] > 0.5f);
      ull bm = __ballot(on);
      if (l == 0) rowb[rl] = bm;                 // row word: bit c = col w*64+c
    }
    __syncthreads();
    if (wv == 0) {
      const ull wc = rowb[l & 31];
      const int hi2 = l >> 5;
      ull* basep = bits + (((size_t)(bb * 32 + w)) << 11) + (size_t)q32 * 32;
      #pragma unroll
      for (int sub = 0; sub < 2; ++sub) {
        #pragma unroll
        for (int r = 0; r < 16; ++r) {
          int pos = sub * 32 + (r & 3) + 8 * (r >> 2) + 4 * hi2;
          ull W = __ballot(((wc >> pos) & 1ull) != 0ull);
          if (l == 0) basep[sub * 16 + r] = W;
        }
      }
    }
  } else if (bx < SEG0 + SEG1) {   // ---- Kf gather (fp32 inputs only)
    if (isb) return;
    unsigned g = (bx - SEG0) * 256u + tid;
    unsigned lane = g & 63u, f = (g >> 6) & 7u, it = (g >> 9) & 31u, bh = g >> 14;
    unsigned t = f >> 2, dc = f & 3, hi = lane >> 5, l31 = lane & 31;
    size_t src = (size_t)bh * (S_LEN * D_DIM) +
                 (size_t)(it * 64 + t * 32 + l31) * D_DIM + dc * 16 + hi * 8;
    *(int4*)&Kf[(size_t)g * 8] = cvt_f8((const float*)Kin + src);
  } else if (bx < SEG0 + SEG1 + SEG2) {  // ---- Vf transpose via LDS
    unsigned idx = bx - (SEG0 + SEG1);
    unsigned bh = idx >> 5, it = idx & 31u;
    {
      int k = tid >> 2, d0 = (tid & 3) * 16;
      size_t src = (size_t)bh * (S_LEN * D_DIM) + (size_t)(it * 64 + k) * D_DIM + d0;
      int4 a, c;
      if (isb) {
        const unsigned short* s = (const unsigned short*)Vin + src;
        a = *(const int4*)s; c = *(const int4*)(s + 8);
      } else {
        const float* s = (const float*)Vin + src;
        a = cvt_f8(s); c = cvt_f8(s + 8);
      }
      *(int4*)&T[k * 72 + d0] = a;
      *(int4*)&T[k * 72 + d0 + 8] = c;
    }
    __syncthreads();
    #pragma unroll
    for (int h = 0; h < 2; ++h) {
      int c = tid + h * 256;
      int lane = c & 63, f = c >> 6;
      int t = f >> 2, kc = (f >> 1) & 1, dt = f & 1;
      int hi = lane >> 5, l31 = lane & 31;
      unsigned short v[8];
      #pragma unroll
      for (int j = 0; j < 8; ++j)
        v[j] = T[(t * 32 + kc * 16 + hi * 8 + j) * 72 + dt * 32 + l31];
      *(int4*)&Vf[(((size_t)(bh * 32 + it)) * 8 + f) * 512 + lane * 8] = *(int4*)v;
    }
  } else {                       // ---- Qc (fp32 inputs only)
    if (isb) return;
    size_t i0 = ((size_t)(bx - (SEG0 + SEG1 + SEG2)) * 256 + tid) * 8;
    unsigned short v[8];
    const float* f = (const float*)Qin + i0;
    #pragma unroll
    for (int j = 0; j < 4; ++j)
      *((unsigned*)v + j) = packbf(f[2 * j] * C1, f[2 * j + 1] * C1);
    *(int4*)&Qc[i0] = *(int4*)v;
  }
}

// ---------------- split-K LDS-staged attention (R15 structure) ----------------
// grid 1024: id -> xcd=id&7, slot=id>>3; bh=(id&7)*4+(slot&3); qb=slot>>2.
// Block = 64 q-rows. Wave w: g=w>>1 sweeps subtiles [g*32,+32), rw=w&1 rows.
// bf16 inputs: K staged DIRECT from K via per-lane gather src; Q read direct.
// Mask: per-phase 16 wave-uniform lane-mask ulls (s_load) + v_cndmask.
// QK^T: two independent 2-deep MFMA chains (sc0/sc1) merged by 16 adds.
__global__ __launch_bounds__(256, 4) void attn_fast(
    const unsigned short* __restrict__ Qc, const void* __restrict__ Qraw,
    const unsigned short* __restrict__ Kf, const void* __restrict__ Kraw,
    const unsigned short* __restrict__ Vf, const ull* __restrict__ Wm,
    const void* __restrict__ maskp, void* __restrict__ Op) {
  __shared__ __align__(16) unsigned short Stg[2][2][8][512]; // [group][buf][frag][1KB]

  const bool isb = detect_bf16(maskp);
  const int tid  = threadIdx.x;
  const int wave = tid >> 6;
  const int lane = tid & 63;
  const int hi   = lane >> 5;
  const int l31  = lane & 31;
  const int wvu  = __builtin_amdgcn_readfirstlane(wave);
  const int g    = wvu >> 1;        // k-half (uniform)
  const int rw   = wvu & 1;         // row-half (uniform)
  const int id   = blockIdx.x;
  const int slot = id >> 3;
  const int bh   = (id & 7) * 4 + (slot & 3);   // XCD-affine: 4 bh per XCD
  const int qb   = slot >> 2;                   // 0..31
  const int qbase = qb * 64 + rw * 32;          // this wave's 32 q-rows
  const int b    = bh >> 4;
  const size_t base = (size_t)bh * S_LEN * D_DIM;
  const int xidx = ((lane ^ 32) & 63) * 4;      // ds_bpermute byte index

  // Q B-fragments: bf16, scaled by C1 (direct-read when bf16 inputs)
  bf16x8 qf[4];
  if (isb) {
    #pragma unroll
    for (int dc = 0; dc < 4; ++dc) {
      bf16x8 q = *(const bf16x8*)((const unsigned short*)Qraw + base +
                    (size_t)(qbase + l31) * D_DIM + dc * 16 + hi * 8);
      #pragma unroll
      for (int j = 0; j < 8; ++j)
        q[j] = (short)f2bf(bf2f((unsigned short)q[j]) * C1);
      qf[dc] = q;
    }
  } else {
    #pragma unroll
    for (int dc = 0; dc < 4; ++dc)
      qf[dc] = *(const bf16x8*)&Qc[base + (size_t)(qbase + l31) * D_DIM + dc * 16 + hi * 8];
  }

  // ones B-fragment (all bf16 1.0) for row-sum MFMA
  bf16x8 onesb;
  #pragma unroll
  for (int i = 0; i < 8; ++i) onesb[i] = (short)0x3F80;

  // K staging source: per-lane gather (bf16 direct) or Kf linear (fp32 path).
  const unsigned short* Kw0;
  size_t kd;
  if (isb) {
    Kw0 = (const unsigned short*)Kraw + base + (size_t)l31 * D_DIM + (2 * rw) * 16 + hi * 8;
    kd = 16;
  } else {
    Kw0 = Kf + (size_t)bh * 131072 + (size_t)(2 * rw) * 512 + lane * 8;
    kd = 512;
  }
  const unsigned short* Vw = Vf + (size_t)bh * 131072 + (size_t)(2 * rw) * 512 + lane * 8;
  const int ks0 = g * 32;

  // wave-uniform lane-mask table base (ull units)
  const ull* WmU = Wm + (((size_t)(b * 32)) << 11) + (size_t)(qb * 2 + rw) * 32;

  f32x16 acc_o[2];   // [dt]: O[m=(reg&3)+8(reg>>2)+4hi][d=dt*32+l31] (unnormalized)
  f32x16 acc_l;      // row-sums, same row mapping
  f32x16 zv;         // persistent zero C-operand
  #pragma unroll
  for (int r = 0; r < 16; ++r) {
    acc_o[0][r] = 0.f; acc_o[1][r] = 0.f; acc_l[r] = 0.f; zv[r] = 0.f;
  }

  // prologue: stage subtile ks0 into buf 0
  {
    const size_t so = (size_t)ks0 * 2048;
    gl_lds16(Kw0 + so,      &Stg[g][0][2 * rw][0]);
    gl_lds16(Kw0 + so + kd, &Stg[g][0][2 * rw + 1][0]);
    gl_lds16(Vw + so,       &Stg[g][0][4 + 2 * rw][0]);
    gl_lds16(Vw + so + 512, &Stg[g][0][4 + 2 * rw + 1][0]);
  }
  __syncthreads();

  #pragma unroll 2
  for (int f = 0; f < 32; ++f) {
    const int cur = f & 1;
    // stage next subtile into the other buffer (flies under this compute)
    if (f < 31) {
      const size_t so = (size_t)(ks0 + f + 1) * 2048;
      gl_lds16(Kw0 + so,      &Stg[g][cur ^ 1][2 * rw][0]);
      gl_lds16(Kw0 + so + kd, &Stg[g][cur ^ 1][2 * rw + 1][0]);
      gl_lds16(Vw + so,       &Stg[g][cur ^ 1][4 + 2 * rw][0]);
      gl_lds16(Vw + so + 512, &Stg[g][cur ^ 1][4 + 2 * rw + 1][0]);
    }
    // per-phase lane-mask words (wave-uniform -> s_load)
    const int ks = ks0 + f;
    const ull* Wp = WmU + (((size_t)(ks >> 1)) << 11) + (size_t)(ks & 1) * 16;

    // QK^T: two independent 2-deep chains (was one 4-deep chain)
    bf16x8 ka[4];
    #pragma unroll
    for (int dc = 0; dc < 4; ++dc)
      ka[dc] = *(const bf16x8*)&Stg[g][cur][dc][lane * 8];
    __builtin_amdgcn_s_setprio(1);
    f32x16 sc0 = mfma32(ka[0], qf[0], zv);
    f32x16 sc1 = mfma32(ka[2], qf[2], zv);
    sc0 = mfma32(ka[1], qf[1], sc0);
    sc1 = mfma32(ka[3], qf[3], sc1);
    __builtin_amdgcn_s_setprio(0);

    // merge halves + exp2 + mask (one cndmask per slot, SGPR-pair mask)
    float p[16];
    #pragma unroll
    for (int r = 0; r < 16; ++r) {
      float e = fexp2(sc0[r] + sc1[r]);
      ull mr = Wp[r];
      asm("v_cndmask_b32 %0, %1, 0, %2" : "=v"(p[r]) : "v"(e), "s"(mr));
    }

    #pragma unroll
    for (int kc = 0; kc < 2; ++kc) {
      unsigned pk0 = packbf(p[8 * kc + 0], p[8 * kc + 1]);
      unsigned pk1 = packbf(p[8 * kc + 2], p[8 * kc + 3]);
      unsigned pk2 = packbf(p[8 * kc + 4], p[8 * kc + 5]);
      unsigned pk3 = packbf(p[8 * kc + 6], p[8 * kc + 7]);
      uint4 d;
#if __has_builtin(__builtin_amdgcn_permlane32_swap)
      uint2v s02 = __builtin_amdgcn_permlane32_swap(pk0, pk2, false, false);
      uint2v s13 = __builtin_amdgcn_permlane32_swap(pk1, pk3, false, false);
      d.x = s02[0]; d.z = s02[1];
      d.y = s13[0]; d.w = s13[1];
#else
      unsigned x0 = (unsigned)__builtin_amdgcn_ds_bpermute(xidx, (int)pk0);
      unsigned x1 = (unsigned)__builtin_amdgcn_ds_bpermute(xidx, (int)pk1);
      unsigned x2 = (unsigned)__builtin_amdgcn_ds_bpermute(xidx, (int)pk2);
      unsigned x3 = (unsigned)__builtin_amdgcn_ds_bpermute(xidx, (int)pk3);
      d.x = hi ? x2 : pk0;
      d.y = hi ? x3 : pk1;
      d.z = hi ? pk2 : x0;
      d.w = hi ? pk3 : x1;
#endif
      bf16x8 pf = __builtin_bit_cast(bf16x8, d);
      __builtin_amdgcn_s_setprio(1);
      #pragma unroll
      for (int dt = 0; dt < 2; ++dt) {
        bf16x8 vfr = *(const bf16x8*)&Stg[g][cur][4 + kc * 2 + dt][lane * 8];
        acc_o[dt] = mfma32(pf, vfr, acc_o[dt]);
      }
      acc_l = mfma32(pf, onesb, acc_l);   // row-sum on the MFMA pipe
      __builtin_amdgcn_s_setprio(0);
    }

    // one barrier per phase: next stage landed + buf[cur] safe to restage
    __syncthreads();
  }

  // ---- cross-group combine via retired Stg (fixed-max softmax -> pure sums)
  float* Cb = (float*)Stg;
  if (g == 1) {
    #pragma unroll
    for (int r = 0; r < 16; ++r) {
      Cb[(rw * 48 + r) * 64 + lane]      = acc_o[0][r];
      Cb[(rw * 48 + 16 + r) * 64 + lane] = acc_o[1][r];
      Cb[(rw * 48 + 32 + r) * 64 + lane] = acc_l[r];
    }
  }
  __syncthreads();
  if (g == 0) {
    #pragma unroll
    for (int r = 0; r < 16; ++r) {
      float o0 = acc_o[0][r] + Cb[(rw * 48 + r) * 64 + lane];
      float o1 = acc_o[1][r] + Cb[(rw * 48 + 16 + r) * 64 + lane];
      float lv = acc_l[r]    + Cb[(rw * 48 + 32 + r) * 64 + lane];
      int m = (r & 3) + 8 * (r >> 2) + 4 * hi;
      float inv = 1.0f / lv;
      size_t idx = base + (size_t)(qbase + m) * D_DIM + l31;
      if (isb) {
        ((unsigned short*)Op)[idx]      = f2bf(o0 * inv);
        ((unsigned short*)Op)[idx + 32] = f2bf(o1 * inv);
      } else {
        ((float*)Op)[idx]      = o0 * inv;
        ((float*)Op)[idx + 32] = o1 * inv;
      }
    }
  }
}

// ---------------- no-workspace fallback (R2-proven structure) ----------------
__global__ __launch_bounds__(256, 2) void attn_fallback(
    const void* __restrict__ Qp, const void* __restrict__ Kp,
    const void* __restrict__ Vp, const void* __restrict__ maskp,
    void* __restrict__ Op) {
  __shared__ __align__(16) short QKlds[128 * 72];
  __shared__ __align__(16) short Vtlds[64 * 72];
  __shared__ __align__(16) short Plds2[128 * 72];

  const bool isb = detect_bf16(maskp);
  const int tid  = threadIdx.x;
  const int wave = tid >> 6;
  const int lane = tid & 63;
  const int l15  = lane & 15;
  const int quad = lane >> 4;
  const int q0   = blockIdx.x * 128;
  const int bh   = blockIdx.y;
  const int b    = bh >> 4;
  const size_t base = (size_t)bh * S_LEN * D_DIM;

  const short* Qs = (const short*)Qp; const float* Qf = (const float*)Qp;
  const short* Ks = (const short*)Kp; const float* Kf2 = (const float*)Kp;
  const short* Vs = (const short*)Vp; const float* Vf2 = (const float*)Vp;

  if (isb) {
    const short* Qg = Qs + base + (size_t)q0 * D_DIM;
    #pragma unroll
    for (int p = 0; p < 4; ++p) {
      int e = p * 2048 + tid * 8;
      *(int4*)&QKlds[(e >> 6) * 72 + (e & 63)] = *(const int4*)(Qg + e);
    }
  } else {
    const float* Qg = Qf + base + (size_t)q0 * D_DIM;
    #pragma unroll
    for (int p = 0; p < 4; ++p) {
      int e = p * 2048 + tid * 8;
      *(int4*)&QKlds[(e >> 6) * 72 + (e & 63)] = cvt_f8(Qg + e);
    }
  }
  __syncthreads();
  bf16x8 qf[2][2];
  #pragma unroll
  for (int mi = 0; mi < 2; ++mi)
    #pragma unroll
    for (int kt = 0; kt < 2; ++kt)
      qf[mi][kt] = *(const bf16x8*)&QKlds[(wave * 32 + mi * 16 + l15) * 72 + kt * 32 + quad * 8];
  __syncthreads();

  f32x4 acc_o[2][4];
  f32x4 acc_l[2];
  const f32x4 zero4 = {0.f, 0.f, 0.f, 0.f};
  #pragma unroll
  for (int mi = 0; mi < 2; ++mi) {
    acc_l[mi] = zero4;
    #pragma unroll
    for (int nt = 0; nt < 4; ++nt) acc_o[mi][nt] = zero4;
  }
  bf16x8 onesB;
  {
    short ov = (l15 == 0) ? (short)0x3F80 : (short)0;
    #pragma unroll
    for (int i = 0; i < 8; ++i) onesB[i] = ov;
  }

  for (int it = 0; it < NIT; ++it) {
    const int k0 = it * 64;
    if (isb) {
      const short* Kg = Ks + base + (size_t)k0 * D_DIM;
      #pragma unroll
      for (int p = 0; p < 2; ++p) {
        int e = p * 2048 + tid * 8;
        *(int4*)&QKlds[(e >> 6) * 72 + (e & 63)] = *(const int4*)(Kg + e);
      }
    } else {
      const float* Kg = Kf2 + base + (size_t)k0 * D_DIM;
      #pragma unroll
      for (int p = 0; p < 2; ++p) {
        int e = p * 2048 + tid * 8;
        *(int4*)&QKlds[(e >> 6) * 72 + (e & 63)] = cvt_f8(Kg + e);
      }
    }
    {
      const int r0 = (tid >> 3) * 2;
      const int d0 = (tid & 7) * 8;
      unsigned short as_[8], bs_[8];
      if (isb) {
        const short* Vg = Vs + base + (size_t)k0 * D_DIM;
        *(int4*)as_ = *(const int4*)(Vg + r0 * D_DIM + d0);
        *(int4*)bs_ = *(const int4*)(Vg + (r0 + 1) * D_DIM + d0);
      } else {
        const float* Vg = Vf2 + base + (size_t)k0 * D_DIM;
        *(int4*)as_ = cvt_f8(Vg + r0 * D_DIM + d0);
        *(int4*)bs_ = cvt_f8(Vg + (r0 + 1) * D_DIM + d0);
      }
      #pragma unroll
      for (int j = 0; j < 8; ++j) {
        int d = d0 + j;
        int blk = (r0 >> 3) ^ (d >> 3);
        unsigned pk = (unsigned)as_[j] | ((unsigned)bs_[j] << 16);
        *(unsigned*)&Vtlds[d * 72 + blk * 8 + (r0 & 7)] = pk;
      }
    }
    __syncthreads();

    f32x4 sc[2][4];
    #pragma unroll
    for (int mi = 0; mi < 2; ++mi)
      #pragma unroll
      for (int nt = 0; nt < 4; ++nt) sc[mi][nt] = zero4;
    #pragma unroll
    for (int nt = 0; nt < 4; ++nt) {
      bf16x8 kf0 = *(const bf16x8*)&QKlds[(nt * 16 + l15) * 72 + quad * 8];
      bf16x8 kf1 = *(const bf16x8*)&QKlds[(nt * 16 + l15) * 72 + 32 + quad * 8];
      #pragma unroll
      for (int mi = 0; mi < 2; ++mi) {
        sc[mi][nt] = mfma16(qf[mi][0], kf0, sc[mi][nt]);
        sc[mi][nt] = mfma16(qf[mi][1], kf1, sc[mi][nt]);
      }
    }

    #pragma unroll
    for (int mi = 0; mi < 2; ++mi) {
      #pragma unroll
      for (int nt = 0; nt < 4; ++nt) {
        #pragma unroll
        for (int reg = 0; reg < 4; ++reg) {
          int rg = q0 + wave * 32 + mi * 16 + quad * 4 + reg;
          size_t mix = (size_t)b * S_LEN * S_LEN + (size_t)rg * S_LEN + k0 + nt * 16 + l15;
          float mv = isb ? bf2f(((const unsigned short*)maskp)[mix])
                         : ((const float*)maskp)[mix];
          float y = sc[mi][nt][reg] * C1 - mv * C2;
          Plds2[(wave * 32 + mi * 16 + quad * 4 + reg) * 72 + nt * 16 + l15] =
              (short)f2bf(fexp2(y));
        }
      }
    }
    __syncthreads();

    #pragma unroll
    for (int kt = 0; kt < 2; ++kt) {
      bf16x8 pf[2];
      #pragma unroll
      for (int mi = 0; mi < 2; ++mi)
        pf[mi] = *(const bf16x8*)&Plds2[(wave * 32 + mi * 16 + l15) * 72 + kt * 32 + quad * 8];
      #pragma unroll
      for (int nt = 0; nt < 4; ++nt) {
        int d = nt * 16 + l15;
        int kb = (kt * 4 + quad) ^ (d >> 3);
        bf16x8 vf = *(const bf16x8*)&Vtlds[d * 72 + kb * 8];
        #pragma unroll
        for (int mi = 0; mi < 2; ++mi)
          acc_o[mi][nt] = mfma16(pf[mi], vf, acc_o[mi][nt]);
      }
      #pragma unroll
      for (int mi = 0; mi < 2; ++mi)
        acc_l[mi] = mfma16(pf[mi], onesB, acc_l[mi]);
    }
    __syncthreads();
  }

  #pragma unroll
  for (int mi = 0; mi < 2; ++mi) {
    #pragma unroll
    for (int reg = 0; reg < 4; ++reg) {
      float lv = __shfl(acc_l[mi][reg], lane & 48, 64);
      float inv = 1.0f / lv;
      #pragma unroll
      for (int nt = 0; nt < 4; ++nt) {
        float o = acc_o[mi][nt][reg] * inv;
        size_t idx = base + (size_t)(q0 + wave * 32 + mi * 16 + quad * 4 + reg) * D_DIM + nt * 16 + l15;
        if (isb) ((unsigned short*)Op)[idx] = f2bf(o);
        else     ((float*)Op)[idx] = o;
      }
    }
  }
}

extern "C" void kernel_launch(void* const* d_in, const int* in_sizes, int n_in,
                              void* d_out, int out_size, void* d_ws, size_t ws_size,
                              hipStream_t stream) {
  const void* Q = d_in[0];
  const void* K = d_in[1];
  const void* V = d_in[2];
  const void* M = d_in[3];

  dim3 block(256);
  const size_t bits_bytes = (size_t)2 * S_LEN * S_LEN / 8;          // 1 MB
  const size_t tens_bytes = (size_t)2 * 16 * S_LEN * D_DIM * 2;     // 8.4 MB bf16

  if (ws_size >= bits_bytes + 3 * tens_bytes) {
    char* ws = (char*)d_ws;
    ull* bits = (ull*)ws;
    unsigned short* Kf = (unsigned short*)(ws + bits_bytes);
    unsigned short* Vf = (unsigned short*)(ws + bits_bytes + tens_bytes);
    unsigned short* Qc = (unsigned short*)(ws + bits_bytes + 2 * tens_bytes);
    prep_all<<<dim3(SEG0 + SEG1 + SEG2 + SEG3), block, 0, stream>>>(
        M, K, V, Q, bits, Kf, Vf, Qc);
    attn_fast<<<dim3(1024), block, 0, stream>>>(Qc, Q, Kf, K, Vf, bits, M, d_out);
  } else {
    attn_fallback<<<dim3(S_LEN / 128, 32), block, 0, stream>>>(Q, K, V, M, d_out);
  }
}